// Round 8
// baseline (236.498 us; speedup 1.0000x reference)
//
#include <hip/hip_runtime.h>

#define DEV __device__ __forceinline__
#define KSIG (-1.442695041f)
#define KTANH (-2.885390082f)

typedef float f2 __attribute__((ext_vector_type(2)));

DEV float fexp2(float x) { return __builtin_amdgcn_exp2f(x); }
DEV float frcp(float x) { return __builtin_amdgcn_rcpf(x); }
DEV float bperm(int a, float x) {
  return __int_as_float(__builtin_amdgcn_ds_bpermute(a, __float_as_int(x)));
}
DEV f2 pkfma(f2 a, f2 b, f2 c) { return __builtin_elementwise_fma(a, b, c); }

// Lane u of a 5-lane group owns state index j=u and gate rows
// {u,5+u,10+u,15+u} (i,f,g,o). kexp folded into weights/bias: sigmoid rows
// scaled by KSIG, g-row by KTANH; act = rcp(1+exp2(acc)), tanh = 2*act-1.
struct CellP {
  f2 wx[4][2];
  f2 wh[4][2];
  float wx4[4], wh4[4];
  f2 b2[4];  // {bias, 0}
};

DEV void load_cellP(CellP& W, int u, const float* __restrict__ Wih,
                    const float* __restrict__ Whh,
                    const float* __restrict__ bih,
                    const float* __restrict__ bhh) {
#pragma unroll
  for (int rt = 0; rt < 4; ++rt) {  // 0=i 1=f 2=g 3=o
    int row = 5 * rt + u;
    float kx = (rt == 2) ? KTANH : KSIG;
    W.wx[rt][0] = (f2){kx * Wih[row * 5 + 0], kx * Wih[row * 5 + 1]};
    W.wx[rt][1] = (f2){kx * Wih[row * 5 + 2], kx * Wih[row * 5 + 3]};
    W.wx4[rt] = kx * Wih[row * 5 + 4];
    W.wh[rt][0] = (f2){kx * Whh[row * 5 + 0], kx * Whh[row * 5 + 1]};
    W.wh[rt][1] = (f2){kx * Whh[row * 5 + 2], kx * Whh[row * 5 + 3]};
    W.wh4[rt] = kx * Whh[row * 5 + 4];
    W.b2[rt] = (f2){kx * (bih[row] + bhh[row]), 0.f};
  }
}

// Two independent cell timesteps (streams A,B) with shared weights,
// manually interleaved so stream B's ops fill stream A's latency bubbles
// (and vice versa). hX: h(t-1) in, h(t) out. hOwnX: this lane's own h_j(t).
DEV void stepP2(const CellP& W, const f2 xA[2], float x4A, const f2 xB[2],
                float x4B, float hA[5], float hB[5], float& cA, float& cB,
                float& hOwnA, float& hOwnB, const int bp[5]) {
  f2 hA0 = (f2){hA[0], hA[1]}, hA1 = (f2){hA[2], hA[3]};
  f2 hB0 = (f2){hB[0], hB[1]}, hB1 = (f2){hB[2], hB[3]};
  float accA[4], accB[4];
#pragma unroll
  for (int rt = 0; rt < 4; ++rt) {
    f2 a = pkfma(W.wx[rt][0], xA[0], W.b2[rt]);
    f2 b = pkfma(W.wx[rt][0], xB[0], W.b2[rt]);
    a = pkfma(W.wx[rt][1], xA[1], a);
    b = pkfma(W.wx[rt][1], xB[1], b);
    a = pkfma(W.wh[rt][0], hA0, a);
    b = pkfma(W.wh[rt][0], hB0, b);
    a = pkfma(W.wh[rt][1], hA1, a);
    b = pkfma(W.wh[rt][1], hB1, b);
    float sa = a.x + a.y;
    float sb = b.x + b.y;
    sa = fmaf(W.wx4[rt], x4A, sa);
    sb = fmaf(W.wx4[rt], x4B, sb);
    accA[rt] = fmaf(W.wh4[rt], hA[4], sa);
    accB[rt] = fmaf(W.wh4[rt], hB[4], sb);
  }
  float giA = frcp(1.f + fexp2(accA[0]));
  float giB = frcp(1.f + fexp2(accB[0]));
  float gfA = frcp(1.f + fexp2(accA[1]));
  float gfB = frcp(1.f + fexp2(accB[1]));
  float ggA = fmaf(2.f, frcp(1.f + fexp2(accA[2])), -1.f);
  float ggB = fmaf(2.f, frcp(1.f + fexp2(accB[2])), -1.f);
  float goA = frcp(1.f + fexp2(accA[3]));
  float goB = frcp(1.f + fexp2(accB[3]));
  cA = fmaf(gfA, cA, giA * ggA);
  cB = fmaf(gfB, cB, giB * ggB);
  float thA = fmaf(2.f, frcp(1.f + fexp2(KTANH * cA)), -1.f);
  float thB = fmaf(2.f, frcp(1.f + fexp2(KTANH * cB)), -1.f);
  hOwnA = goA * thA;
  hOwnB = goB * thB;
#pragma unroll
  for (int u2 = 0; u2 < 5; ++u2) {
    hA[u2] = bperm(bp[u2], hOwnA);
    hB[u2] = bperm(bp[u2], hOwnB);
  }
}

// Block = 192 threads = 3 waves, 24 elements: 12 five-lane groups per wave,
// each lane carrying TWO independent elements (stream A = g, B = 12+g).
// wave0: lstm1. wave1: lstm2a, publishes h2a(t) to sH[t&1]. wave2: lstm2b,
// one step behind, consumes sH[(t+1)&1]. One __syncthreads per timestep.
// FC stack fused at the end, task-split over all 192 lanes.
__global__ __launch_bounds__(192, 4) void rnn2s_kernel(
    const float* __restrict__ x1, const float* __restrict__ x2,
    const float* __restrict__ Wih1, const float* __restrict__ Whh1,
    const float* __restrict__ bih1, const float* __restrict__ bhh1,
    const float* __restrict__ Wih2a, const float* __restrict__ Whh2a,
    const float* __restrict__ bih2a, const float* __restrict__ bhh2a,
    const float* __restrict__ Wih2b, const float* __restrict__ Whh2b,
    const float* __restrict__ bih2b, const float* __restrict__ bhh2b,
    const float* __restrict__ W1, const float* __restrict__ b1,
    const float* __restrict__ W2, const float* __restrict__ b2,
    const float* __restrict__ W3, const float* __restrict__ b3,
    const float* __restrict__ W4, const float* __restrict__ b4,
    const float* __restrict__ W5, const float* __restrict__ b5,
    float* __restrict__ out, int B) {
  __shared__ float sH[2][2][64];  // [buf][stream][g*5+u]; words 60..63 junk
  __shared__ float sIn[24][20];
  __shared__ float sA[24][32];
  __shared__ float sB[24][32];

  const int tid = threadIdx.x;
  const int w = tid >> 6;  // wave role: 0=lstm1 1=lstm2a 2=lstm2b
  const int l = tid & 63;
  const int g = l / 5;
  const int u = l - 5 * g;
  const bool act = (g < 12);
  const int el = act ? g : 11;
  const int eA = blockIdx.x * 24 + el;
  const int eB = eA + 12;
  const int eAc = (eA < B) ? eA : (B - 1);
  const int eBc = (eB < B) ? eB : (B - 1);

  CellP W;
  if (w == 0)
    load_cellP(W, u, Wih1, Whh1, bih1, bhh1);
  else if (w == 1)
    load_cellP(W, u, Wih2a, Whh2a, bih2a, bhh2a);
  else
    load_cellP(W, u, Wih2b, Whh2b, bih2b, bhh2b);

  int bp[5];
#pragma unroll
  for (int u2 = 0; u2 < 5; ++u2) bp[u2] = (5 * g + u2) * 4;

  for (int i = tid; i < 256; i += 192) ((float*)sH)[i] = 0.f;

  float hA[5], hB[5];
  float cA = 0.f, cB = 0.f, hOwnA = 0.f, hOwnB = 0.f;
#pragma unroll
  for (int k = 0; k < 5; ++k) hA[k] = hB[k] = 0.f;

  const float* pxA = ((w == 0) ? x1 : x2) + (size_t)eAc * 640;
  const float* pxB = ((w == 0) ? x1 : x2) + (size_t)eBc * 640;

  f2 xpA[2], xpB[2];
  float x4A = 0.f, x4B = 0.f;
  if (w < 2) {
    xpA[0] = (f2){pxA[0], pxA[1]};
    xpA[1] = (f2){pxA[2], pxA[3]};
    x4A = pxA[4];
    xpB[0] = (f2){pxB[0], pxB[1]};
    xpB[1] = (f2){pxB[2], pxB[3]};
    x4B = pxB[4];
  }
  __syncthreads();  // sH zeroed before wave2's first (junk) read

  for (int t = 0; t < 128; ++t) {
    f2 xinA[2], xinB[2];
    float xin4A, xin4B;
    if (w == 2) {  // h2a(t-1); t=0 reads zeroed buf (junk step, discarded)
      const float* sa_ = &sH[(t + 1) & 1][0][g * 5];
      const float* sb_ = &sH[(t + 1) & 1][1][g * 5];
      xinA[0] = (f2){sa_[0], sa_[1]};
      xinA[1] = (f2){sa_[2], sa_[3]};
      xin4A = sa_[4];
      xinB[0] = (f2){sb_[0], sb_[1]};
      xinB[1] = (f2){sb_[2], sb_[3]};
      xin4B = sb_[4];
    } else {
      xinA[0] = xpA[0];
      xinA[1] = xpA[1];
      xin4A = x4A;
      xinB[0] = xpB[0];
      xinB[1] = xpB[1];
      xin4B = x4B;
    }
    if (w < 2) {  // prefetch x(t+1)
      const int tn = (t < 127) ? t + 1 : 127;
      xpA[0] = (f2){pxA[tn * 5 + 0], pxA[tn * 5 + 1]};
      xpA[1] = (f2){pxA[tn * 5 + 2], pxA[tn * 5 + 3]};
      x4A = pxA[tn * 5 + 4];
      xpB[0] = (f2){pxB[tn * 5 + 0], pxB[tn * 5 + 1]};
      xpB[1] = (f2){pxB[tn * 5 + 2], pxB[tn * 5 + 3]};
      x4B = pxB[tn * 5 + 4];
    }
    stepP2(W, xinA, xin4A, xinB, xin4B, hA, hB, cA, cB, hOwnA, hOwnB, bp);
    if (w == 2 && t == 0) {  // discard the junk step; restart state from 0
#pragma unroll
      for (int k = 0; k < 5; ++k) hA[k] = hB[k] = 0.f;
      cA = cB = 0.f;
      hOwnA = hOwnB = 0.f;
    }
    if (w == 1) {  // publish h2a(t); lanes 60..63 write junk words
      sH[t & 1][0][l] = hOwnA;
      sH[t & 1][1][l] = hOwnB;
    }
    __syncthreads();
  }

  // wave2 trails by one: consume h2a(127) from sH[127&1]=sH[1]
  if (w == 2) {
    const float* sa_ = &sH[1][0][g * 5];
    const float* sb_ = &sH[1][1][g * 5];
    f2 xinA[2] = {(f2){sa_[0], sa_[1]}, (f2){sa_[2], sa_[3]}};
    f2 xinB[2] = {(f2){sb_[0], sb_[1]}, (f2){sb_[2], sb_[3]}};
    stepP2(W, xinA, sa_[4], xinB, sb_[4], hA, hB, cA, cB, hOwnA, hOwnB, bp);
  }

  // Stage FC inputs: [x1_last, x2_last, h1, h2b] for both streams
  if (act) {
    if (w == 0) {
      sIn[el][u] = x1[(size_t)eAc * 640 + 635 + u];
      sIn[el][10 + u] = hOwnA;  // out1 = h1(127), stream A
      sIn[12 + el][u] = x1[(size_t)eBc * 640 + 635 + u];
      sIn[12 + el][10 + u] = hOwnB;
    } else if (w == 1) {
      sIn[el][5 + u] = x2[(size_t)eAc * 640 + 635 + u];
      sIn[12 + el][5 + u] = x2[(size_t)eBc * 640 + 635 + u];
    } else {
      sIn[el][15 + u] = hOwnA;  // out2 = h2b(127)
      sIn[12 + el][15 + u] = hOwnB;
    }
  }
  __syncthreads();

  // FC stack: task-split over 192 lanes; weights from global (L1-cached).
  for (int task = tid; task < 24 * 32; task += 192) {
    int e = task >> 5, n = task & 31;
    float acc = b1[n];
#pragma unroll
    for (int k = 0; k < 20; ++k) acc = fmaf(W1[n * 20 + k], sIn[e][k], acc);
    sA[e][n] = fmaxf(acc, 0.f);
  }
  __syncthreads();
  for (int task = tid; task < 24 * 32; task += 192) {
    int e = task >> 5, n = task & 31;
    float acc = b2[n];
#pragma unroll
    for (int k = 0; k < 32; ++k) acc = fmaf(W2[n * 32 + k], sA[e][k], acc);
    sB[e][n] = fmaxf(acc, 0.f);
  }
  __syncthreads();
  for (int task = tid; task < 24 * 16; task += 192) {
    int e = task >> 4, n = task & 15;
    float acc = b3[n];
#pragma unroll
    for (int k = 0; k < 32; ++k) acc = fmaf(W3[n * 32 + k], sB[e][k], acc);
    sA[e][n] = fmaxf(acc, 0.f);  // reuse sA cols 0..15
  }
  __syncthreads();
  for (int task = tid; task < 24 * 16; task += 192) {
    int e = task >> 4, n = task & 15;
    float acc = b4[n];
#pragma unroll
    for (int k = 0; k < 16; ++k) acc = fmaf(W4[n * 16 + k], sA[e][k], acc);
    sB[e][n] = fmaxf(acc, 0.f);
  }
  __syncthreads();
  if (tid < 120) {  // 24 elems x 5 outputs
    int e = tid / 5, n = tid - 5 * (tid / 5);
    float acc = b5[n];
#pragma unroll
    for (int k = 0; k < 16; ++k) acc = fmaf(W5[n * 16 + k], sB[e][k], acc);
    int ego = blockIdx.x * 24 + e;
    if (ego < B) out[(size_t)ego * 5 + n] = acc;
  }
}

extern "C" void kernel_launch(void* const* d_in, const int* in_sizes, int n_in,
                              void* d_out, int out_size, void* d_ws,
                              size_t ws_size, hipStream_t stream) {
  const float* x1 = (const float*)d_in[0];
  const float* x2 = (const float*)d_in[1];
  const float* Wih1 = (const float*)d_in[2];
  const float* Whh1 = (const float*)d_in[3];
  const float* bih1 = (const float*)d_in[4];
  const float* bhh1 = (const float*)d_in[5];
  const float* Wih2a = (const float*)d_in[6];
  const float* Whh2a = (const float*)d_in[7];
  const float* bih2a = (const float*)d_in[8];
  const float* bhh2a = (const float*)d_in[9];
  const float* Wih2b = (const float*)d_in[10];
  const float* Whh2b = (const float*)d_in[11];
  const float* bih2b = (const float*)d_in[12];
  const float* bhh2b = (const float*)d_in[13];
  const float* W1 = (const float*)d_in[14];
  const float* b1 = (const float*)d_in[15];
  const float* W2 = (const float*)d_in[16];
  const float* b2 = (const float*)d_in[17];
  const float* W3 = (const float*)d_in[18];
  const float* b3 = (const float*)d_in[19];
  const float* W4 = (const float*)d_in[20];
  const float* b4 = (const float*)d_in[21];
  const float* W5 = (const float*)d_in[22];
  const float* b5 = (const float*)d_in[23];

  int B = in_sizes[0] / 640;  // [B,128,5]
  int nB = (B + 23) / 24;     // 24 elements per block (2 streams x 12)

  rnn2s_kernel<<<nB, 192, 0, stream>>>(
      x1, x2, Wih1, Whh1, bih1, bhh1, Wih2a, Whh2a, bih2a, bhh2a, Wih2b, Whh2b,
      bih2b, bhh2b, W1, b1, W2, b2, W3, b3, W4, b4, W5, b5, (float*)d_out, B);
}